// Round 4
// baseline (309.912 us; speedup 1.0000x reference)
//
#include <hip/hip_runtime.h>
#include <stdint.h>

typedef __attribute__((ext_vector_type(8))) short short8;
typedef __attribute__((ext_vector_type(4))) short short4v;
typedef __attribute__((ext_vector_type(4))) float floatx4;

#define DEV static __device__ __forceinline__

DEV unsigned short f2bf(float f) {
  union { float f; uint32_t u; } v; v.f = f;
  return (unsigned short)((v.u + 0x7FFFu + ((v.u >> 16) & 1u)) >> 16);
}
DEV float bf2f(unsigned short h) {
  union { uint32_t u; float f; } v; v.u = ((uint32_t)h) << 16;
  return v.f;
}
DEV uint32_t pk2(float lo, float hi) {
  return (uint32_t)f2bf(lo) | ((uint32_t)f2bf(hi) << 16);
}
DEV void gload_lds16(const void* g, void* l) {
  __builtin_amdgcn_global_load_lds(
      (const __attribute__((address_space(1))) uint32_t*)g,
      (__attribute__((address_space(3))) uint32_t*)l, 16, 0, 0);
}

#if defined(__has_builtin)
#if __has_builtin(__builtin_amdgcn_mfma_f32_16x16x16bf16_1k)
#define HAVE_MFMA16 1
#endif
#endif

DEV floatx4 mfma16(short4v a, short4v b, floatx4 c) {
#ifdef HAVE_MFMA16
  return __builtin_amdgcn_mfma_f32_16x16x16bf16_1k(a, b, c, 0, 0, 0);
#else
  floatx4 d;
  asm volatile("v_mfma_f32_16x16x16_bf16 %0, %1, %2, %3\n\ts_nop 7\n\ts_nop 7"
               : "=v"(d) : "v"(a), "v"(b), "v"(c));
  return d;
#endif
}

// ---------- fp32 -> bf16 convert: [X 4M][wq 1M][wk 1M][wv 1M][wo 1M] ----------
__global__ __launch_bounds__(256) void k_convert(
    const float* __restrict__ X, const float* __restrict__ Wq,
    const float* __restrict__ Wk, const float* __restrict__ Wv,
    const float* __restrict__ Wo, unsigned short* __restrict__ out) {
  long gid = (long)blockIdx.x * 256 + threadIdx.x;
  long e = gid * 8;
  int seg = (int)(e >> 20);
  const float* src; long base;
  if (seg < 4)      { src = X;  base = 0; }
  else if (seg == 4){ src = Wq; base = 4l << 20; }
  else if (seg == 5){ src = Wk; base = 5l << 20; }
  else if (seg == 6){ src = Wv; base = 6l << 20; }
  else              { src = Wo; base = 7l << 20; }
  const float4* s4 = (const float4*)(src + (e - base));
  float4 a = s4[0], b = s4[1];
  union { uint4 q; unsigned short s[8]; } u;
  u.s[0] = f2bf(a.x); u.s[1] = f2bf(a.y); u.s[2] = f2bf(a.z); u.s[3] = f2bf(a.w);
  u.s[4] = f2bf(b.x); u.s[5] = f2bf(b.y); u.s[6] = f2bf(b.z); u.s[7] = f2bf(b.w);
  *(uint4*)(out + e) = u.q;
}

// ---------- GEMM C = A * W^T   (A: MxK bf16 rm, W: NxK bf16 rm) ----------
template <int MODE>
__global__ __launch_bounds__(256) void k_gemm(
    const unsigned short* __restrict__ A,
    const unsigned short* __restrict__ B0, const unsigned short* __restrict__ B1,
    const unsigned short* __restrict__ B2,
    unsigned short* __restrict__ Cq, unsigned short* __restrict__ Ck,
    unsigned short* __restrict__ Cv, float* __restrict__ Cf, int K) {
  __shared__ unsigned short At[128 * 64];
  __shared__ unsigned short Bt[128 * 64];
  const int tid = threadIdx.x, lane = tid & 63, wid = tid >> 6;
  const int wm = (wid >> 1) * 64, wn = (wid & 1) * 64;
  const int g = lane >> 4, c0 = lane & 15;
  const int bm0 = blockIdx.x * 128;
  const int bnG = blockIdx.y * 128;
  const unsigned short* Bp;
  int bn0;
  if constexpr (MODE == 0) {
    int wsel = bnG >> 10;
    Bp = wsel == 0 ? B0 : (wsel == 1 ? B1 : B2);
    bn0 = bnG & 1023;
  } else { Bp = B0; bn0 = bnG; }
  floatx4 acc[4][4] = {};
  for (int kt = 0; kt < K; kt += 64) {
#pragma unroll
    for (int i = 0; i < 4; ++i) {
      int o = (wid * 64 + lane) * 16 + i * 4096;
      int row = o >> 7, k0 = (o & 127) >> 1;
      gload_lds16((const char*)A  + ((long)(bm0 + row) * K + kt + k0) * 2, (char*)At + o);
      gload_lds16((const char*)Bp + ((long)(bn0 + row) * K + kt + k0) * 2, (char*)Bt + o);
    }
    __syncthreads();
#pragma unroll
    for (int kk = 0; kk < 2; ++kk) {
      const int kb = kk * 64 + g * 16;
      short8 av[4], bv[4];
#pragma unroll
      for (int mi = 0; mi < 4; ++mi)
        av[mi] = *(const short8*)((const char*)At + (wm + mi * 16 + c0) * 128 + kb);
#pragma unroll
      for (int ni = 0; ni < 4; ++ni)
        bv[ni] = *(const short8*)((const char*)Bt + (wn + ni * 16 + c0) * 128 + kb);
#pragma unroll
      for (int mi = 0; mi < 4; ++mi)
#pragma unroll
        for (int ni = 0; ni < 4; ++ni)
          acc[mi][ni] = __builtin_amdgcn_mfma_f32_16x16x32_bf16(av[mi], bv[ni], acc[mi][ni], 0, 0, 0);
    }
    __syncthreads();
  }
#pragma unroll
  for (int mi = 0; mi < 4; ++mi)
#pragma unroll
    for (int ni = 0; ni < 4; ++ni)
#pragma unroll
      for (int i = 0; i < 4; ++i) {
        int r = bm0 + wm + mi * 16 + 4 * g + i;
        int cg = bnG + wn + ni * 16 + c0;
        float v = acc[mi][ni][i];
        if constexpr (MODE == 0) {
          int wsel = cg >> 10, cc = cg & 1023, h = cc >> 6, dkk = cc & 63;
          int bb = r >> 11, ll = r & 2047;
          unsigned short* dst = wsel == 0 ? Cq : (wsel == 1 ? Ck : Cv);
          dst[((long)(bb * 16 + h) * 2048 + ll) * 64 + dkk] = f2bf(v);
        } else {
          Cf[(long)r * 1024 + cg] = v;
        }
      }
}

// ---------- RoPE in place on Q||K (contiguous, each [2,16,2048,64] bf16) ----------
__global__ __launch_bounds__(256) void k_rope(unsigned short* __restrict__ QK, float qscale) {
  int gid = blockIdx.x * 256 + threadIdx.x;  // 262144 threads: (row, half)
  int row = gid >> 1, hf = gid & 1;          // rows 0..65535 = Q, rest = K
  float scale = row < 65536 ? qscale : 1.0f;
  int l = row & 2047;
  unsigned short* p = QK + (long)row * 64 + hf * 32;
  union { uint4 q[4]; unsigned short s[32]; } u;
#pragma unroll
  for (int i = 0; i < 4; ++i) u.q[i] = ((const uint4*)p)[i];
  float lf = (float)l;
#pragma unroll
  for (int j = 0; j < 16; ++j) {
    int pp = hf * 16 + j;
    float ang = lf * exp2f(-(float)pp * 0.4152410118609203f);  // log2(10000)/32
    float sv, cv; sincosf(ang, &sv, &cv);
    float x1 = bf2f(u.s[2 * j]), x2 = bf2f(u.s[2 * j + 1]);
    u.s[2 * j]     = f2bf((x1 * cv - x2 * sv) * scale);
    u.s[2 * j + 1] = f2bf((x1 * sv + x2 * cv) * scale);
  }
#pragma unroll
  for (int i = 0; i < 4; ++i) ((uint4*)p)[i] = u.q[i];
}

// ---------- V [bh, 2048, 64] -> V^T [bh, 64, 2048] ----------
__global__ __launch_bounds__(256) void k_transpose(
    const unsigned short* __restrict__ in, unsigned short* __restrict__ out) {
  __shared__ unsigned short t[64][68];
  const int bh = blockIdx.x >> 5, lt = blockIdx.x & 31;
  const int tid = threadIdx.x;
  const unsigned short* src = in + ((long)bh * 2048 + lt * 64) * 64;
#pragma unroll
  for (int p = 0; p < 2; ++p) {
    int idx = tid + p * 256;
    int row = idx >> 3, c = (idx & 7) * 8;
    union { uint4 q; unsigned short s[8]; } u;
    u.q = *(const uint4*)(src + row * 64 + c);
#pragma unroll
    for (int j = 0; j < 8; ++j) t[row][c + j] = u.s[j];
  }
  __syncthreads();
  unsigned short* dst = out + (long)bh * 64 * 2048 + lt * 64;
#pragma unroll
  for (int p = 0; p < 2; ++p) {
    int idx = tid + p * 256;
    int dv = idx >> 3, lc = (idx & 7) * 8;
    union { uint4 q; unsigned short s[8]; } u;
#pragma unroll
    for (int j = 0; j < 8; ++j) u.s[j] = t[lc + j][dv];
    *(uint4*)(dst + (long)dv * 2048 + lc) = u.q;
  }
}

// ---------- causal flash attention: swapped-QK^T, in-register softmax ----------
// 1 wave/block; lane (c0,g) owns q-row q0+c0; S^T[k=tt*16+4g+i][q] in regs.
__global__ __launch_bounds__(64) void k_attn(
    const unsigned short* __restrict__ Q, const unsigned short* __restrict__ K,
    const unsigned short* __restrict__ Vt, unsigned short* __restrict__ O) {
  const int bid = blockIdx.x;             // 4096 blocks
  const int xcd = bid & 7, chunk = bid >> 3;
  const int bh = xcd * 4 + (chunk >> 7);  // 4 heads per XCD -> K+V^T L2-resident
  const int qsub = 127 - (chunk & 127);   // heavy q-subtiles first
  const int lane = threadIdx.x & 63;
  const int g = lane >> 4, c0 = lane & 15;
  const long hoff = (long)bh * 2048 * 64;
  const unsigned short* Qh = Q + hoff;
  const unsigned short* Kh = K + hoff;
  const unsigned short* Vh = Vt + hoff;   // [64][2048]
  const int q0 = qsub * 16;
  const int nt = (q0 >> 6) + 1;

  // Q fragment (B-operand): B[col=c0 -> q=q0+c0][k=g*8+j per kk]
  short8 qf[2];
#pragma unroll
  for (int kk = 0; kk < 2; ++kk)
    qf[kk] = *(const short8*)(Qh + (long)(q0 + c0) * 64 + kk * 32 + g * 8);
  floatx4 ctx[4] = {};  // ctx^T[dv = n*16+4g+i][q=q0+c0]
  float m_ = -1e30f, l_ = 0.f;

#pragma unroll 1
  for (int T = 0; T < nt; ++T) {
    // K fragments (A-operand): A[row=c0 -> k-row][d=g*8+j]
    const unsigned short* kp = Kh + ((long)T * 64 + c0) * 64 + g * 8;
    short8 kf[4][2];
#pragma unroll
    for (int tt = 0; tt < 4; ++tt)
#pragma unroll
      for (int kk = 0; kk < 2; ++kk)
        kf[tt][kk] = *(const short8*)(kp + tt * 1024 + kk * 32);
    // V^T fragments for x16 PV (A-operand): A[row=c0 -> dv][k=g*4+j]
    const unsigned short* vp = Vh + (long)c0 * 2048 + T * 64 + g * 4;
    short4v vf[4][4];
#pragma unroll
    for (int n = 0; n < 4; ++n)
#pragma unroll
      for (int tt = 0; tt < 4; ++tt)
        vf[n][tt] = *(const short4v*)(vp + n * 32768 + tt * 16);

    // S^T = K Q^T (Q pre-scaled by log2e/8): p[tt][i] = S[q0+c0][T*64+tt*16+4g+i]
    floatx4 p[4];
#pragma unroll
    for (int tt = 0; tt < 4; ++tt) {
      floatx4 z = {};
      z = __builtin_amdgcn_mfma_f32_16x16x32_bf16(kf[tt][0], qf[0], z, 0, 0, 0);
      p[tt] = __builtin_amdgcn_mfma_f32_16x16x32_bf16(kf[tt][1], qf[1], p[tt] = z, 0, 0, 0);
    }
    if (T == nt - 1) {
#pragma unroll
      for (int tt = 0; tt < 4; ++tt)
#pragma unroll
        for (int i = 0; i < 4; ++i)
          if (T * 64 + tt * 16 + 4 * g + i > q0 + c0) p[tt][i] = -1e30f;
    }
    // softmax: in-lane tree over 16 + 2 shfl across g
    float a0 = fmaxf(fmaxf(p[0][0], p[0][1]), fmaxf(p[0][2], p[0][3]));
    float a1 = fmaxf(fmaxf(p[1][0], p[1][1]), fmaxf(p[1][2], p[1][3]));
    float a2 = fmaxf(fmaxf(p[2][0], p[2][1]), fmaxf(p[2][2], p[2][3]));
    float a3 = fmaxf(fmaxf(p[3][0], p[3][1]), fmaxf(p[3][2], p[3][3]));
    float mx = fmaxf(fmaxf(a0, a1), fmaxf(a2, a3));
    mx = fmaxf(mx, __shfl_xor(mx, 16));
    mx = fmaxf(mx, __shfl_xor(mx, 32));
    float mn = fmaxf(m_, mx);
    float sc = exp2f(m_ - mn);
    m_ = mn;
#pragma unroll
    for (int tt = 0; tt < 4; ++tt)
#pragma unroll
      for (int i = 0; i < 4; ++i)
        p[tt][i] = exp2f(p[tt][i] - m_);
    float s0 = (p[0][0] + p[0][1]) + (p[0][2] + p[0][3]);
    float s1 = (p[1][0] + p[1][1]) + (p[1][2] + p[1][3]);
    float s2 = (p[2][0] + p[2][1]) + (p[2][2] + p[2][3]);
    float s3 = (p[3][0] + p[3][1]) + (p[3][2] + p[3][3]);
    float r = (s0 + s1) + (s2 + s3);
    r += __shfl_xor(r, 16);
    r += __shfl_xor(r, 32);
    l_ = l_ * sc + r;
#pragma unroll
    for (int n = 0; n < 4; ++n)
#pragma unroll
      for (int i = 0; i < 4; ++i)
        ctx[n][i] *= sc;
    // pack P -> x16 B-operand: pb[tt] = P[q=c0][k=tt*16+4g+j], j=0..3
    short4v pb[4];
#pragma unroll
    for (int tt = 0; tt < 4; ++tt) {
      union { uint32_t u[2]; short4v s; } pu;
      pu.u[0] = pk2(p[tt][0], p[tt][1]);
      pu.u[1] = pk2(p[tt][2], p[tt][3]);
      pb[tt] = pu.s;
    }
    // PV: ctx^T[n] += V^T_frag * P_frag (16x16x16, zero cross-lane)
#pragma unroll
    for (int n = 0; n < 4; ++n)
#pragma unroll
      for (int tt = 0; tt < 4; ++tt)
        ctx[n] = mfma16(vf[n][tt], pb[tt], ctx[n]);
  }
  // epilogue: lane's q-row = q0+c0; dv = n*16+4g+i -> 4 packed b64 stores
  const int b = bh >> 4, h = bh & 15;
  float inv = 1.f / l_;
  unsigned short* orow = O + (long)(b * 2048 + q0 + c0) * 1024 + h * 64 + 4 * g;
#pragma unroll
  for (int n = 0; n < 4; ++n) {
    union { uint32_t u[2]; uint2 q; } pu;
    pu.u[0] = pk2(ctx[n][0] * inv, ctx[n][1] * inv);
    pu.u[1] = pk2(ctx[n][2] * inv, ctx[n][3] * inv);
    *(uint2*)(orow + n * 16) = pu.q;
  }
}

extern "C" void kernel_launch(void* const* d_in, const int* in_sizes, int n_in,
                              void* d_out, int out_size, void* d_ws, size_t ws_size,
                              hipStream_t stream) {
  const float* X  = (const float*)d_in[0];
  const float* Wq = (const float*)d_in[1];
  const float* Wk = (const float*)d_in[2];
  const float* Wv = (const float*)d_in[3];
  const float* Wo = (const float*)d_in[4];
  unsigned short* Xb  = (unsigned short*)d_ws;   // 4M elems (bf16 X; reused as V^T later)
  unsigned short* Wqb = Xb + (4l << 20);
  unsigned short* Wkb = Xb + (5l << 20);
  unsigned short* Wvb = Xb + (6l << 20);
  unsigned short* Wob = Xb + (7l << 20);
  unsigned short* Qw  = Xb + (8l << 20);         // [2,16,2048,64]
  unsigned short* Kw  = Xb + (12l << 20);
  unsigned short* Vw  = Xb + (16l << 20);
  unsigned short* Vtw = Xb;                      // alias: X-bf16 dead after QKV GEMM
  unsigned short* Cw  = Xb + (20l << 20);        // ctx [b,l,1024]
  float* Out = (float*)d_out;

  k_convert<<<4096, 256, 0, stream>>>(X, Wq, Wk, Wv, Wo, Xb);
  k_gemm<0><<<dim3(32, 24), 256, 0, stream>>>(Xb, Wqb, Wkb, Wvb, Qw, Kw, Vw, nullptr, 1024);
  k_rope<<<1024, 256, 0, stream>>>(Qw, 0.18033688011112042f);  // log2(e)/8
  k_transpose<<<1024, 256, 0, stream>>>(Vw, Vtw);
  k_attn<<<4096, 64, 0, stream>>>(Qw, Kw, Vtw, Cw);
  k_gemm<1><<<dim3(32, 8), 256, 0, stream>>>(Cw, Wob, nullptr, nullptr,
                                             nullptr, nullptr, nullptr, Out, 1024);
}

// Round 5
// 177.117 us; speedup vs baseline: 1.7498x; 1.7498x over previous
//
#include <hip/hip_runtime.h>
#include <stdint.h>

typedef __attribute__((ext_vector_type(8))) short short8;
typedef __attribute__((ext_vector_type(4))) float floatx4;
typedef __attribute__((ext_vector_type(16))) float floatx16;

#define DEV static __device__ __forceinline__

DEV unsigned short f2bf(float f) {
  union { float f; uint32_t u; } v; v.f = f;
  return (unsigned short)((v.u + 0x7FFFu + ((v.u >> 16) & 1u)) >> 16);
}
DEV float bf2f(unsigned short h) {
  union { uint32_t u; float f; } v; v.u = ((uint32_t)h) << 16;
  return v.f;
}
DEV uint32_t cvtpk(float lo, float hi) {
  uint32_t d;
  asm("v_cvt_pk_bf16_f32 %0, %1, %2" : "=v"(d) : "v"(lo), "v"(hi));
  return d;
}
DEV void gload_lds16(const void* g, void* l) {
  __builtin_amdgcn_global_load_lds(
      (const __attribute__((address_space(1))) uint32_t*)g,
      (__attribute__((address_space(3))) uint32_t*)l, 16, 0, 0);
}

// ---------- fp32 -> bf16 convert: [X 4M][wq 1M][wk 1M][wv 1M][wo 1M] ----------
__global__ __launch_bounds__(256) void k_convert(
    const float* __restrict__ X, const float* __restrict__ Wq,
    const float* __restrict__ Wk, const float* __restrict__ Wv,
    const float* __restrict__ Wo, unsigned short* __restrict__ out) {
  long gid = (long)blockIdx.x * 256 + threadIdx.x;
  long e = gid * 8;
  int seg = (int)(e >> 20);
  const float* src; long base;
  if (seg < 4)      { src = X;  base = 0; }
  else if (seg == 4){ src = Wq; base = 4l << 20; }
  else if (seg == 5){ src = Wk; base = 5l << 20; }
  else if (seg == 6){ src = Wv; base = 6l << 20; }
  else              { src = Wo; base = 7l << 20; }
  const float4* s4 = (const float4*)(src + (e - base));
  float4 a = s4[0], b = s4[1];
  union { uint4 q; unsigned short s[8]; } u;
  u.s[0] = f2bf(a.x); u.s[1] = f2bf(a.y); u.s[2] = f2bf(a.z); u.s[3] = f2bf(a.w);
  u.s[4] = f2bf(b.x); u.s[5] = f2bf(b.y); u.s[6] = f2bf(b.z); u.s[7] = f2bf(b.w);
  *(uint4*)(out + e) = u.q;
}

// ---------- GEMM C = A * W^T   (A: MxK bf16 rm, W: NxK bf16 rm) ----------
template <int MODE>
__global__ __launch_bounds__(256) void k_gemm(
    const unsigned short* __restrict__ A,
    const unsigned short* __restrict__ B0, const unsigned short* __restrict__ B1,
    const unsigned short* __restrict__ B2,
    unsigned short* __restrict__ Cq, unsigned short* __restrict__ Ck,
    unsigned short* __restrict__ Cv, float* __restrict__ Cf, int K) {
  __shared__ unsigned short At[128 * 64];
  __shared__ unsigned short Bt[128 * 64];
  const int tid = threadIdx.x, lane = tid & 63, wid = tid >> 6;
  const int wm = (wid >> 1) * 64, wn = (wid & 1) * 64;
  const int g = lane >> 4, c0 = lane & 15;
  const int bm0 = blockIdx.x * 128;
  const int bnG = blockIdx.y * 128;
  const unsigned short* Bp;
  int bn0;
  if constexpr (MODE == 0) {
    int wsel = bnG >> 10;
    Bp = wsel == 0 ? B0 : (wsel == 1 ? B1 : B2);
    bn0 = bnG & 1023;
  } else { Bp = B0; bn0 = bnG; }
  floatx4 acc[4][4] = {};
  for (int kt = 0; kt < K; kt += 64) {
#pragma unroll
    for (int i = 0; i < 4; ++i) {
      int o = (wid * 64 + lane) * 16 + i * 4096;
      int row = o >> 7, k0 = (o & 127) >> 1;
      gload_lds16((const char*)A  + ((long)(bm0 + row) * K + kt + k0) * 2, (char*)At + o);
      gload_lds16((const char*)Bp + ((long)(bn0 + row) * K + kt + k0) * 2, (char*)Bt + o);
    }
    __syncthreads();
#pragma unroll
    for (int kk = 0; kk < 2; ++kk) {
      const int kb = kk * 64 + g * 16;
      short8 av[4], bv[4];
#pragma unroll
      for (int mi = 0; mi < 4; ++mi)
        av[mi] = *(const short8*)((const char*)At + (wm + mi * 16 + c0) * 128 + kb);
#pragma unroll
      for (int ni = 0; ni < 4; ++ni)
        bv[ni] = *(const short8*)((const char*)Bt + (wn + ni * 16 + c0) * 128 + kb);
#pragma unroll
      for (int mi = 0; mi < 4; ++mi)
#pragma unroll
        for (int ni = 0; ni < 4; ++ni)
          acc[mi][ni] = __builtin_amdgcn_mfma_f32_16x16x32_bf16(av[mi], bv[ni], acc[mi][ni], 0, 0, 0);
    }
    __syncthreads();
  }
#pragma unroll
  for (int mi = 0; mi < 4; ++mi)
#pragma unroll
    for (int ni = 0; ni < 4; ++ni)
#pragma unroll
      for (int i = 0; i < 4; ++i) {
        int r = bm0 + wm + mi * 16 + 4 * g + i;
        int cg = bnG + wn + ni * 16 + c0;
        float v = acc[mi][ni][i];
        if constexpr (MODE == 0) {
          int wsel = cg >> 10, cc = cg & 1023, h = cc >> 6, dkk = cc & 63;
          int bb = r >> 11, ll = r & 2047;
          unsigned short* dst = wsel == 0 ? Cq : (wsel == 1 ? Ck : Cv);
          dst[((long)(bb * 16 + h) * 2048 + ll) * 64 + dkk] = f2bf(v);
        } else {
          Cf[(long)r * 1024 + cg] = v;
        }
      }
}

// ---------- RoPE in place on Q||K (contiguous, each [2,16,2048,64] bf16) ----------
__global__ __launch_bounds__(256) void k_rope(unsigned short* __restrict__ QK, float qscale) {
  int gid = blockIdx.x * 256 + threadIdx.x;  // 262144 threads: (row, half)
  int row = gid >> 1, hf = gid & 1;          // rows 0..65535 = Q, rest = K
  float scale = row < 65536 ? qscale : 1.0f;
  int l = row & 2047;
  unsigned short* p = QK + (long)row * 64 + hf * 32;
  union { uint4 q[4]; unsigned short s[32]; } u;
#pragma unroll
  for (int i = 0; i < 4; ++i) u.q[i] = ((const uint4*)p)[i];
  float lf = (float)l;
#pragma unroll
  for (int j = 0; j < 16; ++j) {
    int pp = hf * 16 + j;
    float ang = lf * exp2f(-(float)pp * 0.4152410118609203f);  // log2(10000)/32
    float sv, cv; sincosf(ang, &sv, &cv);
    float x1 = bf2f(u.s[2 * j]), x2 = bf2f(u.s[2 * j + 1]);
    u.s[2 * j]     = f2bf((x1 * cv - x2 * sv) * scale);
    u.s[2 * j + 1] = f2bf((x1 * sv + x2 * cv) * scale);
  }
#pragma unroll
  for (int i = 0; i < 4; ++i) ((uint4*)p)[i] = u.q[i];
}

// ---------- V [bh, 2048, 64] -> V^T [bh, 64, 2080] (padded stride vs 4KB alias) ----------
#define VT_STRIDE 2080
__global__ __launch_bounds__(256) void k_transpose(
    const unsigned short* __restrict__ in, unsigned short* __restrict__ out) {
  __shared__ unsigned short t[64][68];
  const int bh = blockIdx.x >> 5, lt = blockIdx.x & 31;
  const int tid = threadIdx.x;
  const unsigned short* src = in + ((long)bh * 2048 + lt * 64) * 64;
#pragma unroll
  for (int p = 0; p < 2; ++p) {
    int idx = tid + p * 256;
    int row = idx >> 3, c = (idx & 7) * 8;
    union { uint4 q; unsigned short s[8]; } u;
    u.q = *(const uint4*)(src + row * 64 + c);
#pragma unroll
    for (int j = 0; j < 8; ++j) t[row][c + j] = u.s[j];
  }
  __syncthreads();
  unsigned short* dst = out + (long)bh * 64 * VT_STRIDE + lt * 64;
#pragma unroll
  for (int p = 0; p < 2; ++p) {
    int idx = tid + p * 256;
    int dv = idx >> 3, lc = (idx & 7) * 8;
    union { uint4 q; unsigned short s[8]; } u;
#pragma unroll
    for (int j = 0; j < 8; ++j) u.s[j] = t[lc + j][dv];
    *(uint4*)(dst + (long)dv * VT_STRIDE + lc) = u.q;
  }
}

// ---------- causal flash attention: 32x32 swapped MFMA, in-register softmax ----------
// 1 wave/block, 32 q-rows per wave. Lane (h=lane>>5, c=lane&31) owns q-row q0+c.
// S^T via mfma_32x32x16(A=K,B=Q): reg r -> kv-local (r&3)+8*(r>>2)+4h, col=c.
// PV B-operand built from packed P dwords with one shfl_xor(32) per pair.
__global__ __launch_bounds__(64) void k_attn(
    const unsigned short* __restrict__ Q, const unsigned short* __restrict__ K,
    const unsigned short* __restrict__ Vt, unsigned short* __restrict__ O) {
  const int bid = blockIdx.x;              // 2048 blocks = 8 XCD * 256
  const int xcd = bid & 7, idx = bid >> 3;
  const int bh = xcd * 4 + (idx >> 6);     // 4 heads per XCD -> K/V L2-resident
  const int qs = 63 - (idx & 63);          // heavy q-subtiles first
  const int lane = threadIdx.x & 63;
  const int h = lane >> 5, c = lane & 31;
  const long hoff = (long)bh * 2048 * 64;
  const unsigned short* Qh = Q + hoff;
  const unsigned short* Kh = K + hoff;
  const unsigned short* Vh = Vt + (long)bh * 64 * VT_STRIDE;
  const int q0 = qs * 32, qabs = q0 + c;
  const int nt = (qs >> 1) + 1;

  // Q fragment (B-operand), hoisted: qf[dseg] = Q[q0+c][dseg*16+8h+j]
  short8 qf[4];
#pragma unroll
  for (int d = 0; d < 4; ++d)
    qf[d] = *(const short8*)(Qh + (long)(q0 + c) * 64 + d * 16 + 8 * h);

  floatx16 ctx0 = {}, ctx1 = {};  // ctx^T[dv][q]: dvs=0 -> dv 0..31, dvs=1 -> 32..63
  float m_ = -1e30f, l_ = 0.f;

#pragma unroll 1
  for (int T = 0; T < nt; ++T) {
    // K fragments (A-operand): kf[kvs][dseg] = K[T*64+kvs*32+c][dseg*16+8h+j]
    const unsigned short* kp = Kh + ((long)T * 64 + c) * 64 + 8 * h;
    short8 kf0[4], kf1[4];
#pragma unroll
    for (int d = 0; d < 4; ++d) kf0[d] = *(const short8*)(kp + d * 16);
#pragma unroll
    for (int d = 0; d < 4; ++d) kf1[d] = *(const short8*)(kp + 32 * 64 + d * 16);
    // S^T tiles
    floatx16 s0 = {}, s1 = {};
#pragma unroll
    for (int d = 0; d < 4; ++d)
      s0 = __builtin_amdgcn_mfma_f32_32x32x16_bf16(kf0[d], qf[d], s0, 0, 0, 0);
#pragma unroll
    for (int d = 0; d < 4; ++d)
      s1 = __builtin_amdgcn_mfma_f32_32x32x16_bf16(kf1[d], qf[d], s1, 0, 0, 0);
    // V^T fragments (A-operand): vf[dvs][kvs*2+kseg] = V^T[dvs*32+c][T*64+kvs*32+kseg*16+8h+j]
    const unsigned short* vp = Vh + (long)c * VT_STRIDE + T * 64 + 8 * h;
    short8 vf0[4], vf1[4];
#pragma unroll
    for (int m = 0; m < 4; ++m) vf0[m] = *(const short8*)(vp + m * 16);
#pragma unroll
    for (int m = 0; m < 4; ++m) vf1[m] = *(const short8*)(vp + 32 * VT_STRIDE + m * 16);

    // causal mask (uniform branch, last tile only)
    if (T == nt - 1) {
      const int kvb = T * 64 + 4 * h;
#pragma unroll
      for (int r = 0; r < 16; ++r) {
        const int off = (r & 3) + 8 * (r >> 2);
        if (kvb + off > qabs) s0[r] = -1e30f;
        if (kvb + 32 + off > qabs) s1[r] = -1e30f;
      }
    }
    // softmax (scalar per lane): in-lane trees + 2 cross-lane ops
    float mx = s0[0];
#pragma unroll
    for (int r = 1; r < 16; ++r) mx = fmaxf(mx, s0[r]);
#pragma unroll
    for (int r = 0; r < 16; ++r) mx = fmaxf(mx, s1[r]);
    mx = fmaxf(mx, __shfl_xor(mx, 32));
    float mn = fmaxf(m_, mx);
    float sc = exp2f(m_ - mn);
    m_ = mn;
#pragma unroll
    for (int r = 0; r < 16; ++r) s0[r] = exp2f(s0[r] - m_);
#pragma unroll
    for (int r = 0; r < 16; ++r) s1[r] = exp2f(s1[r] - m_);
    float rs = 0.f;
#pragma unroll
    for (int r = 0; r < 16; ++r) rs += s0[r] + s1[r];
    rs += __shfl_xor(rs, 32);
    l_ = l_ * sc + rs;
#pragma unroll
    for (int r = 0; r < 16; ++r) { ctx0[r] *= sc; ctx1[r] *= sc; }

    // pack P to bf16 dwords: pd[d] = (k-pair starting at (2d&3)+8*(d>>1)+4h)
    uint32_t pd0[8], pd1[8];
#pragma unroll
    for (int d = 0; d < 8; ++d) {
      pd0[d] = cvtpk(s0[2 * d], s0[2 * d + 1]);
      pd1[d] = cvtpk(s1[2 * d], s1[2 * d + 1]);
    }
    // PV: per kvs-subtile, per kseg: B-frag via 2 shfl_xor(32) + selects
#pragma unroll
    for (int kvs = 0; kvs < 2; ++kvs) {
      const uint32_t* pd = kvs ? pd1 : pd0;
#pragma unroll
      for (int ks = 0; ks < 2; ++ks) {
        uint32_t sel0 = h ? pd[4 * ks]     : pd[4 * ks + 2];
        uint32_t sel1 = h ? pd[4 * ks + 1] : pd[4 * ks + 3];
        uint32_t r0 = __shfl_xor(sel0, 32);
        uint32_t r1 = __shfl_xor(sel1, 32);
        union { uint32_t u[4]; short8 s; } bu;
        bu.u[0] = h ? r0 : pd[4 * ks];
        bu.u[1] = h ? r1 : pd[4 * ks + 1];
        bu.u[2] = h ? pd[4 * ks + 2] : r0;
        bu.u[3] = h ? pd[4 * ks + 3] : r1;
        ctx0 = __builtin_amdgcn_mfma_f32_32x32x16_bf16(vf0[kvs * 2 + ks], bu.s, ctx0, 0, 0, 0);
        ctx1 = __builtin_amdgcn_mfma_f32_32x32x16_bf16(vf1[kvs * 2 + ks], bu.s, ctx1, 0, 0, 0);
      }
    }
  }
  // epilogue: lane owns q-row q0+c; dv = dvs*32 + 8m + 4h + (0..3)
  const int b = bh >> 4, hd = bh & 15;
  float inv = 1.f / l_;
  unsigned short* orow = O + (long)(b * 2048 + q0 + c) * 1024 + hd * 64;
#pragma unroll
  for (int m = 0; m < 4; ++m) {
    uint2 w0, w1;
    w0.x = cvtpk(ctx0[4 * m] * inv, ctx0[4 * m + 1] * inv);
    w0.y = cvtpk(ctx0[4 * m + 2] * inv, ctx0[4 * m + 3] * inv);
    *(uint2*)(orow + 8 * m + 4 * h) = w0;
    w1.x = cvtpk(ctx1[4 * m] * inv, ctx1[4 * m + 1] * inv);
    w1.y = cvtpk(ctx1[4 * m + 2] * inv, ctx1[4 * m + 3] * inv);
    *(uint2*)(orow + 32 + 8 * m + 4 * h) = w1;
  }
}

extern "C" void kernel_launch(void* const* d_in, const int* in_sizes, int n_in,
                              void* d_out, int out_size, void* d_ws, size_t ws_size,
                              hipStream_t stream) {
  const float* X  = (const float*)d_in[0];
  const float* Wq = (const float*)d_in[1];
  const float* Wk = (const float*)d_in[2];
  const float* Wv = (const float*)d_in[3];
  const float* Wo = (const float*)d_in[4];
  unsigned short* Xb  = (unsigned short*)d_ws;   // 4M elems bf16 X
  unsigned short* Wqb = Xb + (4l << 20);
  unsigned short* Wkb = Xb + (5l << 20);
  unsigned short* Wvb = Xb + (6l << 20);
  unsigned short* Wob = Xb + (7l << 20);
  unsigned short* Qw  = Xb + (8l << 20);         // [2,16,2048,64]
  unsigned short* Kw  = Xb + (12l << 20);
  unsigned short* Vw  = Xb + (16l << 20);
  unsigned short* Vtw = Xb;  // V^T [32][64][2080]: aliases X/Wq/Wk/Wv (dead after QKV GEMM)
  unsigned short* Cw  = Xb + (20l << 20);        // ctx [b,l,1024]
  float* Out = (float*)d_out;

  k_convert<<<4096, 256, 0, stream>>>(X, Wq, Wk, Wv, Wo, Xb);
  k_gemm<0><<<dim3(32, 24), 256, 0, stream>>>(Xb, Wqb, Wkb, Wvb, Qw, Kw, Vw, nullptr, 1024);
  k_rope<<<1024, 256, 0, stream>>>(Qw, 0.18033688011112042f);  // log2(e)/8
  k_transpose<<<1024, 256, 0, stream>>>(Vw, Vtw);
  k_attn<<<2048, 64, 0, stream>>>(Qw, Kw, Vtw, Cw);
  k_gemm<1><<<dim3(32, 8), 256, 0, stream>>>(Cw, Wob, nullptr, nullptr,
                                             nullptr, nullptr, nullptr, Out, 1024);
}